// Round 4
// baseline (649.736 us; speedup 1.0000x reference)
//
#include <hip/hip_runtime.h>
#include <math.h>

#define N_ITERS 20
#define PITCH 1032   // E LDS row pitch in halfs (1024+8: de-conflicts row-indexed reads)
#define SMEM_BYTES 142592

typedef short short8 __attribute__((ext_vector_type(8)));    // 8 bf16
typedef _Float16 half8 __attribute__((ext_vector_type(8)));  // 8 fp16
typedef _Float16 half2v __attribute__((ext_vector_type(2)));
typedef float floatx4 __attribute__((ext_vector_type(4)));

__device__ __forceinline__ unsigned short f2bf(float f) {
    unsigned int u = __float_as_uint(f);
    u += 0x7FFFu + ((u >> 16) & 1u);   // RNE
    return (unsigned short)(u >> 16);
}
__device__ __forceinline__ float bf2f(unsigned short u) {
    return __uint_as_float((unsigned int)u << 16);
}

__device__ __forceinline__ float dot8(uint4 e, uint4 v, float s) {
#if __has_builtin(__builtin_amdgcn_fdot2)
    const half2v* ep = (const half2v*)&e;
    const half2v* vp = (const half2v*)&v;
    s = __builtin_amdgcn_fdot2(ep[0], vp[0], s, false);
    s = __builtin_amdgcn_fdot2(ep[1], vp[1], s, false);
    s = __builtin_amdgcn_fdot2(ep[2], vp[2], s, false);
    s = __builtin_amdgcn_fdot2(ep[3], vp[3], s, false);
#else
    const _Float16* ep = (const _Float16*)&e;
    const _Float16* vp = (const _Float16*)&v;
#pragma unroll
    for (int i = 0; i < 8; ++i) s += (float)ep[i] * (float)vp[i];
#endif
    return s;
}

// ---------------- prep ----------------
__global__ __launch_bounds__(256) void convert_x(const float* __restrict__ x,
                                                 unsigned short* __restrict__ xb) {
    const int i = (blockIdx.x * 256 + threadIdx.x) << 4;
    unsigned short tmp[16];
#pragma unroll
    for (int p = 0; p < 4; ++p) {
        float4 f = *(const float4*)&x[i + (p << 2)];
        tmp[p * 4 + 0] = f2bf(f.x); tmp[p * 4 + 1] = f2bf(f.y);
        tmp[p * 4 + 2] = f2bf(f.z); tmp[p * 4 + 3] = f2bf(f.w);
    }
    *(uint4*)&xb[i]     = *(const uint4*)&tmp[0];
    *(uint4*)&xb[i + 8] = *(const uint4*)&tmp[8];
}

__global__ __launch_bounds__(256) void transpose_all(
    const float* __restrict__ Wq, const float* __restrict__ Wk,
    const float* __restrict__ Wv, const float* __restrict__ Wo,
    unsigned short* __restrict__ wqT, unsigned short* __restrict__ wkT,
    unsigned short* __restrict__ wvT, unsigned short* __restrict__ woT)
{
    const int z = blockIdx.z;
    const float* S; unsigned short* D; int rows, cols;
    if (z == 0)      { S = Wq; D = wqT; rows = 1024; cols = 512; }
    else if (z == 1) { S = Wk; D = wkT; rows = 1024; cols = 512; }
    else if (z == 2) { S = Wv; D = wvT; rows = 1024; cols = 512; }
    else             { S = Wo; D = woT; rows = 512;  cols = 1024; }
    const int n0 = blockIdx.x << 5, k0 = blockIdx.y << 5;
    if (n0 >= cols || k0 >= rows) return;
    __shared__ float Tls[32][33];
    const int t = threadIdx.x;
    const int rl = t >> 5, cl = t & 31;
#pragma unroll
    for (int i = 0; i < 4; ++i)
        Tls[rl + (i << 3)][cl] = S[(size_t)(k0 + rl + (i << 3)) * cols + n0 + cl];
    __syncthreads();
#pragma unroll
    for (int i = 0; i < 4; ++i)
        D[(size_t)(n0 + rl + (i << 3)) * rows + k0 + cl] = f2bf(Tls[cl][rl + (i << 3)]);
}

__global__ void zero_init(float* __restrict__ part, unsigned int* __restrict__ ctr) {
    int i = blockIdx.x * 256 + threadIdx.x;
    if (i < 3 * 16 * 1024) part[i] = 0.0f;
    if (i < 16) ctr[i] = 0u;
}

// ---------------- QKV projection: 64x64-tile bf16 MFMA GEMM ----------------
// 768 blocks (3/CU) to hide global-load latency (r3's 192-block version was 5% MfmaUtil)
__global__ __launch_bounds__(256) void qkv64(
    const unsigned short* __restrict__ xb,
    const unsigned short* __restrict__ wqT, const unsigned short* __restrict__ wkT,
    const unsigned short* __restrict__ wvT,
    const float* __restrict__ bq, const float* __restrict__ bk, const float* __restrict__ bv,
    unsigned short* __restrict__ qb, unsigned short* __restrict__ kb,
    unsigned short* __restrict__ vt)
{
    const int pz = blockIdx.z;
    const unsigned short* Bt = (pz == 0) ? wqT : (pz == 1) ? wkT : wvT;
    const float* bias = (pz == 0) ? bq : (pz == 1) ? bk : bv;
    __shared__ __align__(16) unsigned short Als[64 * 72];
    __shared__ __align__(16) unsigned short Bls[64 * 72];
    const int t = threadIdx.x;
    const int m0 = blockIdx.y << 6, n0 = blockIdx.x << 6;
    const int w = t >> 6, lane = t & 63, quad = lane >> 4, l16 = lane & 15;
    const int lrow = t >> 2, lk = (t & 3) << 4;
    floatx4 acc[4] = {};
    for (int k0 = 0; k0 < 1024; k0 += 64) {
        uint4 a0 = *(const uint4*)&xb[(size_t)(m0 + lrow) * 1024 + k0 + lk];
        uint4 a1 = *(const uint4*)&xb[(size_t)(m0 + lrow) * 1024 + k0 + lk + 8];
        uint4 b0 = *(const uint4*)&Bt[(size_t)(n0 + lrow) * 1024 + k0 + lk];
        uint4 b1 = *(const uint4*)&Bt[(size_t)(n0 + lrow) * 1024 + k0 + lk + 8];
        __syncthreads();
        *(uint4*)&Als[lrow * 72 + lk] = a0;
        *(uint4*)&Als[lrow * 72 + lk + 8] = a1;
        *(uint4*)&Bls[lrow * 72 + lk] = b0;
        *(uint4*)&Bls[lrow * 72 + lk + 8] = b1;
        __syncthreads();
        short8 af0 = *(const short8*)&Als[(w * 16 + l16) * 72 + quad * 8];
        short8 af1 = *(const short8*)&Als[(w * 16 + l16) * 72 + 32 + quad * 8];
#pragma unroll
        for (int nt = 0; nt < 4; ++nt) {
            short8 g0 = *(const short8*)&Bls[(nt * 16 + l16) * 72 + quad * 8];
            short8 g1 = *(const short8*)&Bls[(nt * 16 + l16) * 72 + 32 + quad * 8];
            acc[nt] = __builtin_amdgcn_mfma_f32_16x16x32_bf16(af0, g0, acc[nt], 0, 0, 0);
            acc[nt] = __builtin_amdgcn_mfma_f32_16x16x32_bf16(af1, g1, acc[nt], 0, 0, 0);
        }
    }
#pragma unroll
    for (int nt = 0; nt < 4; ++nt) {
        const int gn = n0 + nt * 16 + l16;
        const float bb = bias[gn];
        const int h = gn >> 6, d = gn & 63;
#pragma unroll
        for (int p = 0; p < 4; ++p) {
            const int gm = m0 + w * 16 + quad * 4 + p;
            const int batch = gm >> 10, l = gm & 1023;
            const int bhx = (batch << 3) + h;
            const float val = acc[nt][p] + bb;
            if (pz < 2) {
                unsigned short* dst = (pz == 0) ? qb : kb;
                dst[((size_t)((bhx << 10) + l) << 6) + d] = f2bf(val);
            } else {
                vt[((size_t)bhx << 16) + ((size_t)d << 10) + l] = f2bf(val);  // V^T [bh][d][l]
            }
        }
    }
}

// ---------------- persistent Sinkhorn: E lives in LDS for build+20 iters+attn ----------------
// 256 wgs x 512 thr, cooperative. wg = bh*16+chunk owns rows [chunk*64, chunk*64+64) of head bh.
__global__ __launch_bounds__(512, 1) void sinkhorn_persistent(
    const unsigned short* __restrict__ qb, const unsigned short* __restrict__ kb,
    const unsigned short* __restrict__ vt, unsigned short* __restrict__ o_p,
    float* __restrict__ part, unsigned int* __restrict__ ctr)
{
    extern __shared__ __align__(16) char smem[];
    _Float16* Els = (_Float16*)smem;              // 64*1032*2 = 132096 B
    float*    vls = (float*)(smem + 132096);      // 4096 B
    _Float16* vlh = (_Float16*)(smem + 136192);   // 2048 B
    float*    uls = (float*)(smem + 138240);      // 256 B
    float*    wacc = (float*)(smem + 138496);     // 4096 B  -> total 142592

    const int t = threadIdx.x;
    const int w = t >> 6, lane = t & 63;
    const int quad = lane >> 4, l16 = lane & 15;
    const int rb = w & 3, jh = w >> 2;
    const int wg = blockIdx.x;
    const int bh = wg >> 4, chunk = wg & 15;
    const int m0 = chunk << 6;
    const size_t rowbase = (size_t)bh << 10;

    // ---- phase 1: E = exp(q k^T / 8) -> LDS (wave (rb,jh): rows rb*16.., col-half jh) ----
    {
        const unsigned short* qrow = qb + (rowbase + m0 + rb * 16 + l16) * 64;
        short8 af0 = *(const short8*)(qrow + quad * 8);
        short8 af1 = *(const short8*)(qrow + 32 + quad * 8);
#pragma unroll 2
        for (int jt = 0; jt < 8; ++jt) {
            const int j0 = (jh << 9) + (jt << 6);
#pragma unroll
            for (int nt = 0; nt < 4; ++nt) {
                const unsigned short* krow = kb + (rowbase + j0 + nt * 16 + l16) * 64;
                short8 g0 = *(const short8*)(krow + quad * 8);
                short8 g1 = *(const short8*)(krow + 32 + quad * 8);
                floatx4 c = {0.f, 0.f, 0.f, 0.f};
                c = __builtin_amdgcn_mfma_f32_16x16x32_bf16(af0, g0, c, 0, 0, 0);
                c = __builtin_amdgcn_mfma_f32_16x16x32_bf16(af1, g1, c, 0, 0, 0);
                const int col = j0 + nt * 16 + l16;
#pragma unroll
                for (int p = 0; p < 4; ++p) {
                    const int row = rb * 16 + quad * 4 + p;
                    Els[row * PITCH + col] = (_Float16)__expf(c[p] * 0.125f);
                }
            }
        }
    }
    for (int cc = t; cc < 1024; cc += 512) { vls[cc] = 1.0f; vlh[cc] = (_Float16)1.0f; }
    __syncthreads();

    // ---- phase 2: 20 multiplicative Sinkhorn iterations ----
    const int r0 = w << 3;   // 8 rows per wave
    for (int it = 0; it < N_ITERS; ++it) {
        // zero buffer (it+1)%3 (read at it-2; next written at it+1) -- 3-buffer rotation
        {
            const int zb = (it + 1) % 3;
            if (t < 64)
                __hip_atomic_store(part + zb * 16384 + (bh << 10) + m0 + t, 0.0f,
                                   __ATOMIC_RELAXED, __HIP_MEMORY_SCOPE_AGENT);
        }
        wacc[t] = 0.0f; wacc[t + 512] = 0.0f;
        __syncthreads();

        // row pass: s_i = sum_j E_ij v_j   (E kept in regs for col pass)
        uint4 vh0 = *(const uint4*)(vlh + lane * 8);
        uint4 vh1 = *(const uint4*)(vlh + 512 + lane * 8);
        uint4 e0[8], e1[8];
        float s[8];
#pragma unroll
        for (int rr = 0; rr < 8; ++rr) {
            const _Float16* erow = Els + (r0 + rr) * PITCH;
            e0[rr] = *(const uint4*)(erow + lane * 8);
            e1[rr] = *(const uint4*)(erow + 512 + lane * 8);
            float ss = 0.0f;
            ss = dot8(e0[rr], vh0, ss);
            ss = dot8(e1[rr], vh1, ss);
            s[rr] = ss;
        }
#pragma unroll
        for (int off = 32; off > 0; off >>= 1)
#pragma unroll
            for (int rr = 0; rr < 8; ++rr)
                s[rr] += __shfl_xor(s[rr], off);
        float u_r[8];
#pragma unroll
        for (int rr = 0; rr < 8; ++rr) {
            u_r[rr] = 1.0f / s[rr];
            if (lane == 0) uls[r0 + rr] = u_r[rr];
        }
        // col pass: acc_j += E_ij * u_i
        float acc[16] = {};
#pragma unroll
        for (int rr = 0; rr < 8; ++rr) {
            const _Float16* ep0 = (const _Float16*)&e0[rr];
            const _Float16* ep1 = (const _Float16*)&e1[rr];
#pragma unroll
            for (int k = 0; k < 8; ++k) {
                acc[k]     += (float)ep0[k] * u_r[rr];
                acc[8 + k] += (float)ep1[k] * u_r[rr];
            }
        }
#pragma unroll
        for (int k = 0; k < 8; ++k) {
            atomicAdd(&wacc[lane * 8 + k], acc[k]);            // ds_add_f32
            atomicAdd(&wacc[512 + lane * 8 + k], acc[8 + k]);
        }
        __syncthreads();
        // cross-wg column reduction via device-scope fp32 atomics
        float* pb = part + (it % 3) * 16384 + (bh << 10);
        unsafeAtomicAdd(&pb[t], wacc[t]);
        unsafeAtomicAdd(&pb[t + 512], wacc[t + 512]);
        __syncthreads();
        // per-bh barrier over 16 wgs (monotonic counter)
        if (t == 0) {
            __hip_atomic_fetch_add(&ctr[bh], 1u, __ATOMIC_RELEASE, __HIP_MEMORY_SCOPE_AGENT);
            const unsigned int target = 16u * (unsigned)(it + 1);
            while (__hip_atomic_load(&ctr[bh], __ATOMIC_ACQUIRE, __HIP_MEMORY_SCOPE_AGENT) < target)
                __builtin_amdgcn_s_sleep(2);
        }
        __syncthreads();
        // v update (redundant per wg of same bh -- consistent by construction)
        for (int cc = t; cc < 1024; cc += 512) {
            const float sv = __hip_atomic_load(&pb[cc], __ATOMIC_RELAXED, __HIP_MEMORY_SCOPE_AGENT);
            const float vv = 1.0f / sv;
            vls[cc] = vv;
            vlh[cc] = (_Float16)vv;
        }
        __syncthreads();
    }

    // ---- phase 3: out_pre = diag(u) * (E * diag(v)) @ V  via fp16 MFMA ----
    // A = raw fp16 E from LDS (no per-element work); v folded into B; u folded into epilogue.
    {
        const unsigned short* vtb = vt + ((size_t)bh << 16);
        const int arow = rb * 16 + l16;
        const _Float16* Ea = Els + arow * PITCH;
        floatx4 oacc0 = {0.f, 0.f, 0.f, 0.f}, oacc1 = {0.f, 0.f, 0.f, 0.f};
        const int d0 = (jh * 2) * 16 + l16;
        const int d1 = (jh * 2 + 1) * 16 + l16;
#pragma unroll 4
        for (int k0 = 0; k0 < 1024; k0 += 32) {
            half8 afr = *(const half8*)(Ea + k0 + quad * 8);
            float vkf[8];
            *(float4*)&vkf[0] = *(const float4*)(vls + k0 + quad * 8);
            *(float4*)&vkf[4] = *(const float4*)(vls + k0 + quad * 8 + 4);
            uint4 b0 = *(const uint4*)(vtb + ((size_t)d0 << 10) + k0 + quad * 8);
            uint4 b1 = *(const uint4*)(vtb + ((size_t)d1 << 10) + k0 + quad * 8);
            const unsigned short* bu0 = (const unsigned short*)&b0;
            const unsigned short* bu1 = (const unsigned short*)&b1;
            half8 bf0, bf1;
#pragma unroll
            for (int j = 0; j < 8; ++j) {
                bf0[j] = (_Float16)(bf2f(bu0[j]) * vkf[j]);
                bf1[j] = (_Float16)(bf2f(bu1[j]) * vkf[j]);
            }
            oacc0 = __builtin_amdgcn_mfma_f32_16x16x32_f16(afr, bf0, oacc0, 0, 0, 0);
            oacc1 = __builtin_amdgcn_mfma_f32_16x16x32_f16(afr, bf1, oacc1, 0, 0, 0);
        }
        const int b = bh >> 3, h = bh & 7;
#pragma unroll
        for (int p = 0; p < 4; ++p) {
            const int lrow = m0 + rb * 16 + quad * 4 + p;
            const float uu = uls[rb * 16 + quad * 4 + p];
            const size_t base = ((size_t)((b << 10) + lrow)) * 512 + (h << 6);
            o_p[base + (jh * 2) * 16 + l16]     = f2bf(oacc0[p] * uu);
            o_p[base + (jh * 2 + 1) * 16 + l16] = f2bf(oacc1[p] * uu);
        }
    }
}

// ---------------- out = o_p(bf16 2048x512) @ Wo + bo : 64x64-tile MFMA ----------------
__global__ __launch_bounds__(256) void out64(
    const unsigned short* __restrict__ A, const unsigned short* __restrict__ BT,
    const float* __restrict__ bo, float* __restrict__ C)
{
    __shared__ __align__(16) unsigned short Als[64 * 72];
    __shared__ __align__(16) unsigned short Bls[64 * 72];
    const int t = threadIdx.x;
    const int m0 = blockIdx.y << 6, n0 = blockIdx.x << 6;
    const int w = t >> 6, lane = t & 63, quad = lane >> 4, l16 = lane & 15;
    const int lrow = t >> 2, lk = (t & 3) << 4;
    floatx4 acc[4] = {};
    for (int k0 = 0; k0 < 512; k0 += 64) {
        uint4 a0 = *(const uint4*)&A[(size_t)(m0 + lrow) * 512 + k0 + lk];
        uint4 a1 = *(const uint4*)&A[(size_t)(m0 + lrow) * 512 + k0 + lk + 8];
        uint4 b0 = *(const uint4*)&BT[(size_t)(n0 + lrow) * 512 + k0 + lk];
        uint4 b1 = *(const uint4*)&BT[(size_t)(n0 + lrow) * 512 + k0 + lk + 8];
        __syncthreads();
        *(uint4*)&Als[lrow * 72 + lk] = a0;
        *(uint4*)&Als[lrow * 72 + lk + 8] = a1;
        *(uint4*)&Bls[lrow * 72 + lk] = b0;
        *(uint4*)&Bls[lrow * 72 + lk + 8] = b1;
        __syncthreads();
        short8 af0 = *(const short8*)&Als[(w * 16 + l16) * 72 + quad * 8];
        short8 af1 = *(const short8*)&Als[(w * 16 + l16) * 72 + 32 + quad * 8];
#pragma unroll
        for (int nt = 0; nt < 4; ++nt) {
            short8 g0 = *(const short8*)&Bls[(nt * 16 + l16) * 72 + quad * 8];
            short8 g1 = *(const short8*)&Bls[(nt * 16 + l16) * 72 + 32 + quad * 8];
            acc[nt] = __builtin_amdgcn_mfma_f32_16x16x32_bf16(af0, g0, acc[nt], 0, 0, 0);
            acc[nt] = __builtin_amdgcn_mfma_f32_16x16x32_bf16(af1, g1, acc[nt], 0, 0, 0);
        }
    }
#pragma unroll
    for (int nt = 0; nt < 4; ++nt) {
        const int gn = n0 + nt * 16 + l16;
        const float bb = bo[gn];
#pragma unroll
        for (int p = 0; p < 4; ++p) {
            const int gm = m0 + w * 16 + quad * 4 + p;
            C[(size_t)gm * 1024 + gn] = acc[nt][p] + bb;
        }
    }
}

extern "C" void kernel_launch(void* const* d_in, const int* in_sizes, int n_in,
                              void* d_out, int out_size, void* d_ws, size_t ws_size,
                              hipStream_t stream)
{
    const float* x  = (const float*)d_in[0];
    const float* Wq = (const float*)d_in[1];
    const float* bq = (const float*)d_in[2];
    const float* Wk = (const float*)d_in[3];
    const float* bk = (const float*)d_in[4];
    const float* Wv = (const float*)d_in[5];
    const float* bv = (const float*)d_in[6];
    const float* Wo = (const float*)d_in[7];
    const float* bo = (const float*)d_in[8];
    float* out = (float*)d_out;

    char* W = (char*)d_ws;
    unsigned short* xb  = (unsigned short*)(W);                    // 4 MB
    unsigned short* wqT = (unsigned short*)(W + (4ll  << 20));     // 1 MB
    unsigned short* wkT = (unsigned short*)(W + (5ll  << 20));     // 1 MB
    unsigned short* wvT = (unsigned short*)(W + (6ll  << 20));     // 1 MB
    unsigned short* woT = (unsigned short*)(W + (7ll  << 20));     // 1 MB
    unsigned short* qb  = (unsigned short*)(W + (8ll  << 20));     // 2 MB
    unsigned short* kb  = (unsigned short*)(W + (10ll << 20));     // 2 MB
    unsigned short* vt  = (unsigned short*)(W + (12ll << 20));     // 2 MB
    unsigned short* o_p = (unsigned short*)(W + (14ll << 20));     // 2 MB
    float* part         = (float*)(W + (16ll << 20));              // 192 KB (3 bufs)
    unsigned int* ctr   = (unsigned int*)(W + (17ll << 20));       // 64 B

    convert_x<<<512, 256, 0, stream>>>(x, xb);
    transpose_all<<<dim3(32, 32, 4), 256, 0, stream>>>(Wq, Wk, Wv, Wo, wqT, wkT, wvT, woT);
    zero_init<<<192, 256, 0, stream>>>(part, ctr);
    qkv64<<<dim3(8, 32, 3), 256, 0, stream>>>(xb, wqT, wkT, wvT, bq, bk, bv, qb, kb, vt);

    hipFuncSetAttribute((const void*)sinkhorn_persistent,
                        hipFuncAttributeMaxDynamicSharedMemorySize, SMEM_BYTES);
    void* kargs[] = { (void*)&qb, (void*)&kb, (void*)&vt, (void*)&o_p,
                      (void*)&part, (void*)&ctr };
    hipLaunchCooperativeKernel((const void*)sinkhorn_persistent, dim3(256), dim3(512),
                               kargs, SMEM_BYTES, stream);

    out64<<<dim3(16, 32), 256, 0, stream>>>(o_p, woT, bo, out);
}

// Round 5
// 557.648 us; speedup vs baseline: 1.1651x; 1.1651x over previous
//
#include <hip/hip_runtime.h>
#include <math.h>

#define N_ITERS 20
#define PITCH 1032   // E LDS row pitch in halfs (1024+8)
#define SMEM_BYTES 142592

typedef short short8 __attribute__((ext_vector_type(8)));    // 8 bf16
typedef _Float16 half8 __attribute__((ext_vector_type(8)));  // 8 fp16
typedef _Float16 half2v __attribute__((ext_vector_type(2)));
typedef float floatx4 __attribute__((ext_vector_type(4)));

__device__ __forceinline__ unsigned short f2bf(float f) {
    unsigned int u = __float_as_uint(f);
    u += 0x7FFFu + ((u >> 16) & 1u);   // RNE
    return (unsigned short)(u >> 16);
}
__device__ __forceinline__ float bf2f(unsigned short u) {
    return __uint_as_float((unsigned int)u << 16);
}

__device__ __forceinline__ float dot8(uint4 e, uint4 v, float s) {
#if __has_builtin(__builtin_amdgcn_fdot2)
    const half2v* ep = (const half2v*)&e;
    const half2v* vp = (const half2v*)&v;
    s = __builtin_amdgcn_fdot2(ep[0], vp[0], s, false);
    s = __builtin_amdgcn_fdot2(ep[1], vp[1], s, false);
    s = __builtin_amdgcn_fdot2(ep[2], vp[2], s, false);
    s = __builtin_amdgcn_fdot2(ep[3], vp[3], s, false);
#else
    const _Float16* ep = (const _Float16*)&e;
    const _Float16* vp = (const _Float16*)&v;
#pragma unroll
    for (int i = 0; i < 8; ++i) s += (float)ep[i] * (float)vp[i];
#endif
    return s;
}

// ---------------- prep ----------------
__global__ __launch_bounds__(256) void convert_x(const float* __restrict__ x,
                                                 unsigned short* __restrict__ xb) {
    const int i = (blockIdx.x * 256 + threadIdx.x) << 4;
    unsigned short tmp[16];
#pragma unroll
    for (int p = 0; p < 4; ++p) {
        float4 f = *(const float4*)&x[i + (p << 2)];
        tmp[p * 4 + 0] = f2bf(f.x); tmp[p * 4 + 1] = f2bf(f.y);
        tmp[p * 4 + 2] = f2bf(f.z); tmp[p * 4 + 3] = f2bf(f.w);
    }
    *(uint4*)&xb[i]     = *(const uint4*)&tmp[0];
    *(uint4*)&xb[i + 8] = *(const uint4*)&tmp[8];
}

__global__ __launch_bounds__(256) void transpose_all(
    const float* __restrict__ Wq, const float* __restrict__ Wk,
    const float* __restrict__ Wv, const float* __restrict__ Wo,
    unsigned short* __restrict__ wqT, unsigned short* __restrict__ wkT,
    unsigned short* __restrict__ wvT, unsigned short* __restrict__ woT)
{
    const int z = blockIdx.z;
    const float* S; unsigned short* D; int rows, cols;
    if (z == 0)      { S = Wq; D = wqT; rows = 1024; cols = 512; }
    else if (z == 1) { S = Wk; D = wkT; rows = 1024; cols = 512; }
    else if (z == 2) { S = Wv; D = wvT; rows = 1024; cols = 512; }
    else             { S = Wo; D = woT; rows = 512;  cols = 1024; }
    const int n0 = blockIdx.x << 5, k0 = blockIdx.y << 5;
    if (n0 >= cols || k0 >= rows) return;
    __shared__ float Tls[32][33];
    const int t = threadIdx.x;
    const int rl = t >> 5, cl = t & 31;
#pragma unroll
    for (int i = 0; i < 4; ++i)
        Tls[rl + (i << 3)][cl] = S[(size_t)(k0 + rl + (i << 3)) * cols + n0 + cl];
    __syncthreads();
#pragma unroll
    for (int i = 0; i < 4; ++i)
        D[(size_t)(n0 + rl + (i << 3)) * rows + k0 + cl] = f2bf(Tls[cl][rl + (i << 3)]);
}

__global__ void zero_init(float* __restrict__ part, unsigned int* __restrict__ ctr) {
    int i = blockIdx.x * 256 + threadIdx.x;
    if (i < 3 * 16 * 1024) part[i] = 0.0f;
    if (i < 16) ctr[i] = 0u;
}

// ---------------- QKV projection: 64x64-tile bf16 MFMA GEMM ----------------
__global__ __launch_bounds__(256) void qkv64(
    const unsigned short* __restrict__ xb,
    const unsigned short* __restrict__ wqT, const unsigned short* __restrict__ wkT,
    const unsigned short* __restrict__ wvT,
    const float* __restrict__ bq, const float* __restrict__ bk, const float* __restrict__ bv,
    unsigned short* __restrict__ qb, unsigned short* __restrict__ kb,
    unsigned short* __restrict__ vt)
{
    const int pz = blockIdx.z;
    const unsigned short* Bt = (pz == 0) ? wqT : (pz == 1) ? wkT : wvT;
    const float* bias = (pz == 0) ? bq : (pz == 1) ? bk : bv;
    __shared__ __align__(16) unsigned short Als[64 * 72];
    __shared__ __align__(16) unsigned short Bls[64 * 72];
    const int t = threadIdx.x;
    const int m0 = blockIdx.y << 6, n0 = blockIdx.x << 6;
    const int w = t >> 6, lane = t & 63, quad = lane >> 4, l16 = lane & 15;
    const int lrow = t >> 2, lk = (t & 3) << 4;
    floatx4 acc[4] = {};
    for (int k0 = 0; k0 < 1024; k0 += 64) {
        uint4 a0 = *(const uint4*)&xb[(size_t)(m0 + lrow) * 1024 + k0 + lk];
        uint4 a1 = *(const uint4*)&xb[(size_t)(m0 + lrow) * 1024 + k0 + lk + 8];
        uint4 b0 = *(const uint4*)&Bt[(size_t)(n0 + lrow) * 1024 + k0 + lk];
        uint4 b1 = *(const uint4*)&Bt[(size_t)(n0 + lrow) * 1024 + k0 + lk + 8];
        __syncthreads();
        *(uint4*)&Als[lrow * 72 + lk] = a0;
        *(uint4*)&Als[lrow * 72 + lk + 8] = a1;
        *(uint4*)&Bls[lrow * 72 + lk] = b0;
        *(uint4*)&Bls[lrow * 72 + lk + 8] = b1;
        __syncthreads();
        short8 af0 = *(const short8*)&Als[(w * 16 + l16) * 72 + quad * 8];
        short8 af1 = *(const short8*)&Als[(w * 16 + l16) * 72 + 32 + quad * 8];
#pragma unroll
        for (int nt = 0; nt < 4; ++nt) {
            short8 g0 = *(const short8*)&Bls[(nt * 16 + l16) * 72 + quad * 8];
            short8 g1 = *(const short8*)&Bls[(nt * 16 + l16) * 72 + 32 + quad * 8];
            acc[nt] = __builtin_amdgcn_mfma_f32_16x16x32_bf16(af0, g0, acc[nt], 0, 0, 0);
            acc[nt] = __builtin_amdgcn_mfma_f32_16x16x32_bf16(af1, g1, acc[nt], 0, 0, 0);
        }
    }
#pragma unroll
    for (int nt = 0; nt < 4; ++nt) {
        const int gn = n0 + nt * 16 + l16;
        const float bb = bias[gn];
        const int h = gn >> 6, d = gn & 63;
#pragma unroll
        for (int p = 0; p < 4; ++p) {
            const int gm = m0 + w * 16 + quad * 4 + p;
            const int batch = gm >> 10, l = gm & 1023;
            const int bhx = (batch << 3) + h;
            const float val = acc[nt][p] + bb;
            if (pz < 2) {
                unsigned short* dst = (pz == 0) ? qb : kb;
                dst[((size_t)((bhx << 10) + l) << 6) + d] = f2bf(val);
            } else {
                vt[((size_t)bhx << 16) + ((size_t)d << 10) + l] = f2bf(val);  // V^T [bh][d][l]
            }
        }
    }
}

// ---------------- persistent Sinkhorn ----------------
// All cross-wg DATA moves via coherence-point (LLC) atomics: unsafeAtomicAdd +
// relaxed agent atomic load/store. Barrier is fully RELAXED: __syncthreads drains
// vmcnt(0) so prior atomics are performed at LLC before the counter increment.
// (r4's ACQUIRE-in-poll-loop emitted an L2 invalidate per poll -> 500us stall.)
__global__ __launch_bounds__(512, 1) void sinkhorn_persistent(
    const unsigned short* __restrict__ qb, const unsigned short* __restrict__ kb,
    const unsigned short* __restrict__ vt, unsigned short* __restrict__ o_p,
    float* __restrict__ part, unsigned int* __restrict__ ctr)
{
    extern __shared__ __align__(16) char smem[];
    _Float16* Els = (_Float16*)smem;              // 64*1032*2 = 132096 B
    float*    vls = (float*)(smem + 132096);      // 4096 B
    _Float16* vlh = (_Float16*)(smem + 136192);   // 2048 B
    float*    uls = (float*)(smem + 138240);      // 256 B
    float*    wacc = (float*)(smem + 138496);     // 4096 B (bank-permuted: col c at (c&7)*128+(c>>3))

    const int t = threadIdx.x;
    const int w = t >> 6, lane = t & 63;
    const int quad = lane >> 4, l16 = lane & 15;
    const int rb = w & 3, jh = w >> 2;
    const int wg = blockIdx.x;
    const int bh = wg >> 4, chunk = wg & 15;
    const int m0 = chunk << 6;
    const size_t rowbase = (size_t)bh << 10;

    // ---- phase 1: E = exp(q k^T / 8) -> LDS ----
    {
        const unsigned short* qrow = qb + (rowbase + m0 + rb * 16 + l16) * 64;
        short8 af0 = *(const short8*)(qrow + quad * 8);
        short8 af1 = *(const short8*)(qrow + 32 + quad * 8);
#pragma unroll 2
        for (int jt = 0; jt < 8; ++jt) {
            const int j0 = (jh << 9) + (jt << 6);
#pragma unroll
            for (int nt = 0; nt < 4; ++nt) {
                const unsigned short* krow = kb + (rowbase + j0 + nt * 16 + l16) * 64;
                short8 g0 = *(const short8*)(krow + quad * 8);
                short8 g1 = *(const short8*)(krow + 32 + quad * 8);
                floatx4 c = {0.f, 0.f, 0.f, 0.f};
                c = __builtin_amdgcn_mfma_f32_16x16x32_bf16(af0, g0, c, 0, 0, 0);
                c = __builtin_amdgcn_mfma_f32_16x16x32_bf16(af1, g1, c, 0, 0, 0);
                const int col = j0 + nt * 16 + l16;
#pragma unroll
                for (int p = 0; p < 4; ++p) {
                    const int row = rb * 16 + quad * 4 + p;
                    Els[row * PITCH + col] = (_Float16)__expf(c[p] * 0.125f);
                }
            }
        }
    }
    for (int cc = t; cc < 1024; cc += 512) { vls[cc] = 1.0f; vlh[cc] = (_Float16)1.0f; }
    __syncthreads();

    // ---- phase 2: 20 multiplicative Sinkhorn iterations ----
    const int r0 = w << 3;   // 8 rows per wave, processed in 2 batches of 4
    for (int it = 0; it < N_ITERS; ++it) {
        {   // zero buffer (it+1)%3  (3-buffer rotation; safety proof in r4 notes)
            const int zb = (it + 1) % 3;
            if (t < 64)
                __hip_atomic_store(part + zb * 16384 + (bh << 10) + m0 + t, 0.0f,
                                   __ATOMIC_RELAXED, __HIP_MEMORY_SCOPE_AGENT);
        }
        wacc[t] = 0.0f; wacc[t + 512] = 0.0f;
        __syncthreads();

        uint4 vh0 = *(const uint4*)(vlh + lane * 8);
        uint4 vh1 = *(const uint4*)(vlh + 512 + lane * 8);
        float acc[16] = {};
#pragma unroll
        for (int half = 0; half < 2; ++half) {
            uint4 e0[4], e1[4];
            float s[4];
#pragma unroll
            for (int rr = 0; rr < 4; ++rr) {
                const _Float16* erow = Els + (r0 + half * 4 + rr) * PITCH;
                e0[rr] = *(const uint4*)(erow + lane * 8);
                e1[rr] = *(const uint4*)(erow + 512 + lane * 8);
                float ss = 0.0f;
                ss = dot8(e0[rr], vh0, ss);
                ss = dot8(e1[rr], vh1, ss);
                s[rr] = ss;
            }
#pragma unroll
            for (int off = 32; off > 0; off >>= 1)
#pragma unroll
                for (int rr = 0; rr < 4; ++rr)
                    s[rr] += __shfl_xor(s[rr], off);
#pragma unroll
            for (int rr = 0; rr < 4; ++rr) {
                const float ui = 1.0f / s[rr];
                if (lane == 0) uls[r0 + half * 4 + rr] = ui;
                const _Float16* ep0 = (const _Float16*)&e0[rr];
                const _Float16* ep1 = (const _Float16*)&e1[rr];
#pragma unroll
                for (int k = 0; k < 8; ++k) {        // v_fma_mix_f32 candidates
                    acc[k]     += (float)ep0[k] * ui;
                    acc[8 + k] += (float)ep1[k] * ui;
                }
            }
        }
        // LDS col accumulation, bank-permuted: col lane*8+k -> wacc[k*128+lane] (2-way, free)
#pragma unroll
        for (int k = 0; k < 8; ++k) {
            atomicAdd(&wacc[k * 128 + lane], acc[k]);
            atomicAdd(&wacc[k * 128 + 64 + lane], acc[8 + k]);
        }
        __syncthreads();
        // cross-wg column reduction via LLC fp32 atomics (read wacc at permuted index)
        float* pb = part + (it % 3) * 16384 + (bh << 10);
        unsafeAtomicAdd(&pb[t],       wacc[(t & 7) * 128 + (t >> 3)]);
        unsafeAtomicAdd(&pb[t + 512], wacc[(t & 7) * 128 + 64 + (t >> 3)]);
        __syncthreads();   // drains vmcnt(0): adds performed at LLC before increment
        // per-bh relaxed barrier over 16 wgs (monotonic counter, no cache maintenance)
        if (t == 0) {
            __hip_atomic_fetch_add(&ctr[bh], 1u, __ATOMIC_RELAXED, __HIP_MEMORY_SCOPE_AGENT);
            const unsigned int target = 16u * (unsigned)(it + 1);
            while (__hip_atomic_load(&ctr[bh], __ATOMIC_RELAXED, __HIP_MEMORY_SCOPE_AGENT) < target)
                __builtin_amdgcn_s_sleep(2);
        }
        __syncthreads();
        // v update (atomic loads hit LLC directly -- no L2 staleness possible)
        for (int cc = t; cc < 1024; cc += 512) {
            const float sv = __hip_atomic_load(&pb[cc], __ATOMIC_RELAXED, __HIP_MEMORY_SCOPE_AGENT);
            const float vv = 1.0f / sv;
            vls[cc] = vv;
            vlh[cc] = (_Float16)vv;
        }
        __syncthreads();
    }

    // ---- phase 3: out_pre = diag(u) * (E * diag(v)) @ V  via fp16 MFMA ----
    {
        const unsigned short* vtb = vt + ((size_t)bh << 16);
        const int arow = rb * 16 + l16;
        const _Float16* Ea = Els + arow * PITCH;
        floatx4 oacc0 = {0.f, 0.f, 0.f, 0.f}, oacc1 = {0.f, 0.f, 0.f, 0.f};
        const int d0 = (jh * 2) * 16 + l16;
        const int d1 = (jh * 2 + 1) * 16 + l16;
#pragma unroll 4
        for (int k0 = 0; k0 < 1024; k0 += 32) {
            half8 afr = *(const half8*)(Ea + k0 + quad * 8);
            float vkf[8];
            *(float4*)&vkf[0] = *(const float4*)(vls + k0 + quad * 8);
            *(float4*)&vkf[4] = *(const float4*)(vls + k0 + quad * 8 + 4);
            uint4 b0 = *(const uint4*)(vtb + ((size_t)d0 << 10) + k0 + quad * 8);
            uint4 b1 = *(const uint4*)(vtb + ((size_t)d1 << 10) + k0 + quad * 8);
            const unsigned short* bu0 = (const unsigned short*)&b0;
            const unsigned short* bu1 = (const unsigned short*)&b1;
            half8 bf0, bf1;
#pragma unroll
            for (int j = 0; j < 8; ++j) {
                bf0[j] = (_Float16)(bf2f(bu0[j]) * vkf[j]);
                bf1[j] = (_Float16)(bf2f(bu1[j]) * vkf[j]);
            }
            oacc0 = __builtin_amdgcn_mfma_f32_16x16x32_f16(afr, bf0, oacc0, 0, 0, 0);
            oacc1 = __builtin_amdgcn_mfma_f32_16x16x32_f16(afr, bf1, oacc1, 0, 0, 0);
        }
        const int b = bh >> 3, h = bh & 7;
#pragma unroll
        for (int p = 0; p < 4; ++p) {
            const int lrow = m0 + rb * 16 + quad * 4 + p;
            const float uu = uls[rb * 16 + quad * 4 + p];
            const size_t base = ((size_t)((b << 10) + lrow)) * 512 + (h << 6);
            o_p[base + (jh * 2) * 16 + l16]     = f2bf(oacc0[p] * uu);
            o_p[base + (jh * 2 + 1) * 16 + l16] = f2bf(oacc1[p] * uu);
        }
    }
}

// ---------------- out = o_p(bf16 2048x512) @ Wo + bo : 64x64-tile MFMA ----------------
__global__ __launch_bounds__(256) void out64(
    const unsigned short* __restrict__ A, const unsigned short* __restrict__ BT,
    const float* __restrict__ bo, float* __restrict__ C)
{
    __shared__ __align__(16) unsigned short Als[64 * 72];
    __shared__ __align__(16) unsigned short Bls[64 * 72];
    const int t = threadIdx.x;
    const int m0 = blockIdx.y << 6, n0 = blockIdx.x << 6;
    const int w = t >> 6, lane = t & 63, quad = lane >> 4, l16 = lane & 15;
    const int lrow = t >> 2, lk = (t & 3) << 4;
    floatx4 acc[4] = {};
    for (int k0 = 0; k0 < 512; k0 += 64) {
        uint4 a0 = *(const uint4*)&A[(size_t)(m0 + lrow) * 512 + k0 + lk];
        uint4 a1 = *(const uint4*)&A[(size_t)(m0 + lrow) * 512 + k0 + lk + 8];
        uint4 b0 = *(const uint4*)&BT[(size_t)(n0 + lrow) * 512 + k0 + lk];
        uint4 b1 = *(const uint4*)&BT[(size_t)(n0 + lrow) * 512 + k0 + lk + 8];
        __syncthreads();
        *(uint4*)&Als[lrow * 72 + lk] = a0;
        *(uint4*)&Als[lrow * 72 + lk + 8] = a1;
        *(uint4*)&Bls[lrow * 72 + lk] = b0;
        *(uint4*)&Bls[lrow * 72 + lk + 8] = b1;
        __syncthreads();
        short8 af0 = *(const short8*)&Als[(w * 16 + l16) * 72 + quad * 8];
        short8 af1 = *(const short8*)&Als[(w * 16 + l16) * 72 + 32 + quad * 8];
#pragma unroll
        for (int nt = 0; nt < 4; ++nt) {
            short8 g0 = *(const short8*)&Bls[(nt * 16 + l16) * 72 + quad * 8];
            short8 g1 = *(const short8*)&Bls[(nt * 16 + l16) * 72 + 32 + quad * 8];
            acc[nt] = __builtin_amdgcn_mfma_f32_16x16x32_bf16(af0, g0, acc[nt], 0, 0, 0);
            acc[nt] = __builtin_amdgcn_mfma_f32_16x16x32_bf16(af1, g1, acc[nt], 0, 0, 0);
        }
    }
#pragma unroll
    for (int nt = 0; nt < 4; ++nt) {
        const int gn = n0 + nt * 16 + l16;
        const float bb = bo[gn];
#pragma unroll
        for (int p = 0; p < 4; ++p) {
            const int gm = m0 + w * 16 + quad * 4 + p;
            C[(size_t)gm * 1024 + gn] = acc[nt][p] + bb;
        }
    }
}

extern "C" void kernel_launch(void* const* d_in, const int* in_sizes, int n_in,
                              void* d_out, int out_size, void* d_ws, size_t ws_size,
                              hipStream_t stream)
{
    const float* x  = (const float*)d_in[0];
    const float* Wq = (const float*)d_in[1];
    const float* bq = (const float*)d_in[2];
    const float* Wk = (const float*)d_in[3];
    const float* bk = (const float*)d_in[4];
    const float* Wv = (const float*)d_in[5];
    const float* bv = (const float*)d_in[6];
    const float* Wo = (const float*)d_in[7];
    const float* bo = (const float*)d_in[8];
    float* out = (float*)d_out;

    char* W = (char*)d_ws;
    unsigned short* xb  = (unsigned short*)(W);                    // 4 MB
    unsigned short* wqT = (unsigned short*)(W + (4ll  << 20));     // 1 MB
    unsigned short* wkT = (unsigned short*)(W + (5ll  << 20));     // 1 MB
    unsigned short* wvT = (unsigned short*)(W + (6ll  << 20));     // 1 MB
    unsigned short* woT = (unsigned short*)(W + (7ll  << 20));     // 1 MB
    unsigned short* qb  = (unsigned short*)(W + (8ll  << 20));     // 2 MB
    unsigned short* kb  = (unsigned short*)(W + (10ll << 20));     // 2 MB
    unsigned short* vt  = (unsigned short*)(W + (12ll << 20));     // 2 MB
    unsigned short* o_p = (unsigned short*)(W + (14ll << 20));     // 2 MB
    float* part         = (float*)(W + (16ll << 20));              // 192 KB (3 bufs)
    unsigned int* ctr   = (unsigned int*)(W + (17ll << 20));       // 64 B

    convert_x<<<512, 256, 0, stream>>>(x, xb);
    transpose_all<<<dim3(32, 32, 4), 256, 0, stream>>>(Wq, Wk, Wv, Wo, wqT, wkT, wvT, woT);
    zero_init<<<192, 256, 0, stream>>>(part, ctr);
    qkv64<<<dim3(8, 32, 3), 256, 0, stream>>>(xb, wqT, wkT, wvT, bq, bk, bv, qb, kb, vt);

    hipFuncSetAttribute((const void*)sinkhorn_persistent,
                        hipFuncAttributeMaxDynamicSharedMemorySize, SMEM_BYTES);
    void* kargs[] = { (void*)&qb, (void*)&kb, (void*)&vt, (void*)&o_p,
                      (void*)&part, (void*)&ctr };
    hipLaunchCooperativeKernel((const void*)sinkhorn_persistent, dim3(256), dim3(512),
                               kargs, SMEM_BYTES, stream);

    out64<<<dim3(16, 32), 256, 0, stream>>>(o_p, woT, bo, out);
}

// Round 6
// 449.211 us; speedup vs baseline: 1.4464x; 1.2414x over previous
//
#include <hip/hip_runtime.h>
#include <math.h>

#define N_ITERS 20
#define PITCH 1032   // E LDS row pitch in halfs (1024+8)
#define SMEM_BYTES 142592
#define CTR_STRIDE 64   // 256B per bh counter line: kills the spinlock line convoy

typedef short short8 __attribute__((ext_vector_type(8)));    // 8 bf16
typedef _Float16 half8 __attribute__((ext_vector_type(8)));  // 8 fp16
typedef _Float16 half2v __attribute__((ext_vector_type(2)));
typedef float floatx4 __attribute__((ext_vector_type(4)));

__device__ __forceinline__ unsigned short f2bf(float f) {
    unsigned int u = __float_as_uint(f);
    u += 0x7FFFu + ((u >> 16) & 1u);   // RNE
    return (unsigned short)(u >> 16);
}
__device__ __forceinline__ float bf2f(unsigned short u) {
    return __uint_as_float((unsigned int)u << 16);
}

__device__ __forceinline__ float dot8(uint4 e, uint4 v, float s) {
#if __has_builtin(__builtin_amdgcn_fdot2)
    const half2v* ep = (const half2v*)&e;
    const half2v* vp = (const half2v*)&v;
    s = __builtin_amdgcn_fdot2(ep[0], vp[0], s, false);
    s = __builtin_amdgcn_fdot2(ep[1], vp[1], s, false);
    s = __builtin_amdgcn_fdot2(ep[2], vp[2], s, false);
    s = __builtin_amdgcn_fdot2(ep[3], vp[3], s, false);
#else
    const _Float16* ep = (const _Float16*)&e;
    const _Float16* vp = (const _Float16*)&v;
#pragma unroll
    for (int i = 0; i < 8; ++i) s += (float)ep[i] * (float)vp[i];
#endif
    return s;
}

// ---------------- prep ----------------
__global__ __launch_bounds__(256) void convert_x(const float* __restrict__ x,
                                                 unsigned short* __restrict__ xb) {
    const int i = (blockIdx.x * 256 + threadIdx.x) << 4;
    unsigned short tmp[16];
#pragma unroll
    for (int p = 0; p < 4; ++p) {
        float4 f = *(const float4*)&x[i + (p << 2)];
        tmp[p * 4 + 0] = f2bf(f.x); tmp[p * 4 + 1] = f2bf(f.y);
        tmp[p * 4 + 2] = f2bf(f.z); tmp[p * 4 + 3] = f2bf(f.w);
    }
    *(uint4*)&xb[i]     = *(const uint4*)&tmp[0];
    *(uint4*)&xb[i + 8] = *(const uint4*)&tmp[8];
}

__global__ __launch_bounds__(256) void transpose_all(
    const float* __restrict__ Wq, const float* __restrict__ Wk,
    const float* __restrict__ Wv, const float* __restrict__ Wo,
    unsigned short* __restrict__ wqT, unsigned short* __restrict__ wkT,
    unsigned short* __restrict__ wvT, unsigned short* __restrict__ woT)
{
    const int z = blockIdx.z;
    const float* S; unsigned short* D; int rows, cols;
    if (z == 0)      { S = Wq; D = wqT; rows = 1024; cols = 512; }
    else if (z == 1) { S = Wk; D = wkT; rows = 1024; cols = 512; }
    else if (z == 2) { S = Wv; D = wvT; rows = 1024; cols = 512; }
    else             { S = Wo; D = woT; rows = 512;  cols = 1024; }
    const int n0 = blockIdx.x << 5, k0 = blockIdx.y << 5;
    if (n0 >= cols || k0 >= rows) return;
    __shared__ float Tls[32][33];
    const int t = threadIdx.x;
    const int rl = t >> 5, cl = t & 31;
#pragma unroll
    for (int i = 0; i < 4; ++i)
        Tls[rl + (i << 3)][cl] = S[(size_t)(k0 + rl + (i << 3)) * cols + n0 + cl];
    __syncthreads();
#pragma unroll
    for (int i = 0; i < 4; ++i)
        D[(size_t)(n0 + rl + (i << 3)) * rows + k0 + cl] = f2bf(Tls[cl][rl + (i << 3)]);
}

__global__ void zero_init(float* __restrict__ part, unsigned int* __restrict__ ctr) {
    int i = blockIdx.x * 256 + threadIdx.x;
    if (i < 3 * 16 * 1024) part[i] = 0.0f;
    if (i < 16 * CTR_STRIDE) ctr[i] = 0u;
}

// ---------------- QKV projection: 64x64-tile bf16 MFMA GEMM ----------------
__global__ __launch_bounds__(256) void qkv64(
    const unsigned short* __restrict__ xb,
    const unsigned short* __restrict__ wqT, const unsigned short* __restrict__ wkT,
    const unsigned short* __restrict__ wvT,
    const float* __restrict__ bq, const float* __restrict__ bk, const float* __restrict__ bv,
    unsigned short* __restrict__ qb, unsigned short* __restrict__ kb,
    unsigned short* __restrict__ vt)
{
    const int pz = blockIdx.z;
    const unsigned short* Bt = (pz == 0) ? wqT : (pz == 1) ? wkT : wvT;
    const float* bias = (pz == 0) ? bq : (pz == 1) ? bk : bv;
    __shared__ __align__(16) unsigned short Als[64 * 72];
    __shared__ __align__(16) unsigned short Bls[64 * 72];
    const int t = threadIdx.x;
    const int m0 = blockIdx.y << 6, n0 = blockIdx.x << 6;
    const int w = t >> 6, lane = t & 63, quad = lane >> 4, l16 = lane & 15;
    const int lrow = t >> 2, lk = (t & 3) << 4;
    floatx4 acc[4] = {};
    for (int k0 = 0; k0 < 1024; k0 += 64) {
        uint4 a0 = *(const uint4*)&xb[(size_t)(m0 + lrow) * 1024 + k0 + lk];
        uint4 a1 = *(const uint4*)&xb[(size_t)(m0 + lrow) * 1024 + k0 + lk + 8];
        uint4 b0 = *(const uint4*)&Bt[(size_t)(n0 + lrow) * 1024 + k0 + lk];
        uint4 b1 = *(const uint4*)&Bt[(size_t)(n0 + lrow) * 1024 + k0 + lk + 8];
        __syncthreads();
        *(uint4*)&Als[lrow * 72 + lk] = a0;
        *(uint4*)&Als[lrow * 72 + lk + 8] = a1;
        *(uint4*)&Bls[lrow * 72 + lk] = b0;
        *(uint4*)&Bls[lrow * 72 + lk + 8] = b1;
        __syncthreads();
        short8 af0 = *(const short8*)&Als[(w * 16 + l16) * 72 + quad * 8];
        short8 af1 = *(const short8*)&Als[(w * 16 + l16) * 72 + 32 + quad * 8];
#pragma unroll
        for (int nt = 0; nt < 4; ++nt) {
            short8 g0 = *(const short8*)&Bls[(nt * 16 + l16) * 72 + quad * 8];
            short8 g1 = *(const short8*)&Bls[(nt * 16 + l16) * 72 + 32 + quad * 8];
            acc[nt] = __builtin_amdgcn_mfma_f32_16x16x32_bf16(af0, g0, acc[nt], 0, 0, 0);
            acc[nt] = __builtin_amdgcn_mfma_f32_16x16x32_bf16(af1, g1, acc[nt], 0, 0, 0);
        }
    }
#pragma unroll
    for (int nt = 0; nt < 4; ++nt) {
        const int gn = n0 + nt * 16 + l16;
        const float bb = bias[gn];
        const int h = gn >> 6, d = gn & 63;
#pragma unroll
        for (int p = 0; p < 4; ++p) {
            const int gm = m0 + w * 16 + quad * 4 + p;
            const int batch = gm >> 10, l = gm & 1023;
            const int bhx = (batch << 3) + h;
            const float val = acc[nt][p] + bb;
            if (pz < 2) {
                unsigned short* dst = (pz == 0) ? qb : kb;
                dst[((size_t)((bhx << 10) + l) << 6) + d] = f2bf(val);
            } else {
                vt[((size_t)bhx << 16) + ((size_t)d << 10) + l] = f2bf(val);  // V^T [bh][d][l]
            }
        }
    }
}

// ---------------- persistent Sinkhorn ----------------
// Cross-wg data via LLC atomics (unsafeAtomicAdd + relaxed agent load/store).
// Barrier: relaxed monotonic counter, ONE 256B LINE PER BH (r5 put all 16
// counters in one line -> 256 pollers convoyed every fetch_add ~10-20us/iter).
__global__ __launch_bounds__(512, 1) void sinkhorn_persistent(
    const unsigned short* __restrict__ qb, const unsigned short* __restrict__ kb,
    const unsigned short* __restrict__ vt, unsigned short* __restrict__ o_p,
    float* __restrict__ part, unsigned int* __restrict__ ctr)
{
    extern __shared__ __align__(16) char smem[];
    _Float16* Els = (_Float16*)smem;              // 64*1032*2 = 132096 B
    float*    vls = (float*)(smem + 132096);      // 4096 B
    _Float16* vlh = (_Float16*)(smem + 136192);   // 2048 B
    float*    uls = (float*)(smem + 138240);      // 256 B
    float*    wacc = (float*)(smem + 138496);     // 4096 B (bank-permuted)

    const int t = threadIdx.x;
    const int w = t >> 6, lane = t & 63;
    const int quad = lane >> 4, l16 = lane & 15;
    const int rb = w & 3, jh = w >> 2;
    const int wg = blockIdx.x;
    const int bh = wg >> 4, chunk = wg & 15;
    const int m0 = chunk << 6;
    const size_t rowbase = (size_t)bh << 10;

    // ---- phase 1: E = exp(q k^T / 8) -> LDS ----
    {
        const unsigned short* qrow = qb + (rowbase + m0 + rb * 16 + l16) * 64;
        short8 af0 = *(const short8*)(qrow + quad * 8);
        short8 af1 = *(const short8*)(qrow + 32 + quad * 8);
#pragma unroll 2
        for (int jt = 0; jt < 8; ++jt) {
            const int j0 = (jh << 9) + (jt << 6);
#pragma unroll
            for (int nt = 0; nt < 4; ++nt) {
                const unsigned short* krow = kb + (rowbase + j0 + nt * 16 + l16) * 64;
                short8 g0 = *(const short8*)(krow + quad * 8);
                short8 g1 = *(const short8*)(krow + 32 + quad * 8);
                floatx4 c = {0.f, 0.f, 0.f, 0.f};
                c = __builtin_amdgcn_mfma_f32_16x16x32_bf16(af0, g0, c, 0, 0, 0);
                c = __builtin_amdgcn_mfma_f32_16x16x32_bf16(af1, g1, c, 0, 0, 0);
                const int col = j0 + nt * 16 + l16;
#pragma unroll
                for (int p = 0; p < 4; ++p) {
                    const int row = rb * 16 + quad * 4 + p;
                    Els[row * PITCH + col] = (_Float16)__expf(c[p] * 0.125f);
                }
            }
        }
    }
    for (int cc = t; cc < 1024; cc += 512) { vls[cc] = 1.0f; vlh[cc] = (_Float16)1.0f; }
    __syncthreads();

    // ---- phase 2: 20 multiplicative Sinkhorn iterations ----
    const int r0 = w << 3;   // 8 rows per wave, 2 batches of 4
    for (int it = 0; it < N_ITERS; ++it) {
        {   // zero buffer (it+1)%3  (3-buffer rotation)
            const int zb = (it + 1) % 3;
            if (t < 64)
                __hip_atomic_store(part + zb * 16384 + (bh << 10) + m0 + t, 0.0f,
                                   __ATOMIC_RELAXED, __HIP_MEMORY_SCOPE_AGENT);
        }
        wacc[t] = 0.0f; wacc[t + 512] = 0.0f;
        __syncthreads();

        uint4 vh0 = *(const uint4*)(vlh + lane * 8);
        uint4 vh1 = *(const uint4*)(vlh + 512 + lane * 8);
        float acc[16] = {};
#pragma unroll
        for (int half = 0; half < 2; ++half) {
            uint4 e0[4], e1[4];
            float s[4];
#pragma unroll
            for (int rr = 0; rr < 4; ++rr) {
                const _Float16* erow = Els + (r0 + half * 4 + rr) * PITCH;
                e0[rr] = *(const uint4*)(erow + lane * 8);
                e1[rr] = *(const uint4*)(erow + 512 + lane * 8);
                float ss = 0.0f;
                ss = dot8(e0[rr], vh0, ss);
                ss = dot8(e1[rr], vh1, ss);
                s[rr] = ss;
            }
#pragma unroll
            for (int off = 32; off > 0; off >>= 1)
#pragma unroll
                for (int rr = 0; rr < 4; ++rr)
                    s[rr] += __shfl_xor(s[rr], off);
#pragma unroll
            for (int rr = 0; rr < 4; ++rr) {
                const float ui = 1.0f / s[rr];
                if (lane == 0) uls[r0 + half * 4 + rr] = ui;
                const _Float16* ep0 = (const _Float16*)&e0[rr];
                const _Float16* ep1 = (const _Float16*)&e1[rr];
#pragma unroll
                for (int k = 0; k < 8; ++k) {
                    acc[k]     += (float)ep0[k] * ui;
                    acc[8 + k] += (float)ep1[k] * ui;
                }
            }
        }
#pragma unroll
        for (int k = 0; k < 8; ++k) {
            atomicAdd(&wacc[k * 128 + lane], acc[k]);
            atomicAdd(&wacc[k * 128 + 64 + lane], acc[8 + k]);
        }
        __syncthreads();
        float* pb = part + (it % 3) * 16384 + (bh << 10);
        unsafeAtomicAdd(&pb[t],       wacc[(t & 7) * 128 + (t >> 3)]);
        unsafeAtomicAdd(&pb[t + 512], wacc[(t & 7) * 128 + 64 + (t >> 3)]);
        __syncthreads();   // drains vmcnt(0): adds performed at LLC before increment
        // per-bh relaxed barrier, padded counter line
        if (t == 0) {
            __hip_atomic_fetch_add(&ctr[bh * CTR_STRIDE], 1u,
                                   __ATOMIC_RELAXED, __HIP_MEMORY_SCOPE_AGENT);
            const unsigned int target = 16u * (unsigned)(it + 1);
            while (__hip_atomic_load(&ctr[bh * CTR_STRIDE],
                                     __ATOMIC_RELAXED, __HIP_MEMORY_SCOPE_AGENT) < target)
                __builtin_amdgcn_s_sleep(2);
        }
        __syncthreads();
        for (int cc = t; cc < 1024; cc += 512) {
            const float sv = __hip_atomic_load(&pb[cc], __ATOMIC_RELAXED, __HIP_MEMORY_SCOPE_AGENT);
            const float vv = 1.0f / sv;
            vls[cc] = vv;
            vlh[cc] = (_Float16)vv;
        }
        __syncthreads();
    }

    // ---- phase 3: out_pre = diag(u) * (E * diag(v)) @ V  via fp16 MFMA ----
    {
        const unsigned short* vtb = vt + ((size_t)bh << 16);
        const int arow = rb * 16 + l16;
        const _Float16* Ea = Els + arow * PITCH;
        floatx4 oacc0 = {0.f, 0.f, 0.f, 0.f}, oacc1 = {0.f, 0.f, 0.f, 0.f};
        const int d0 = (jh * 2) * 16 + l16;
        const int d1 = (jh * 2 + 1) * 16 + l16;
#pragma unroll 4
        for (int k0 = 0; k0 < 1024; k0 += 32) {
            half8 afr = *(const half8*)(Ea + k0 + quad * 8);
            float vkf[8];
            *(float4*)&vkf[0] = *(const float4*)(vls + k0 + quad * 8);
            *(float4*)&vkf[4] = *(const float4*)(vls + k0 + quad * 8 + 4);
            uint4 b0 = *(const uint4*)(vtb + ((size_t)d0 << 10) + k0 + quad * 8);
            uint4 b1 = *(const uint4*)(vtb + ((size_t)d1 << 10) + k0 + quad * 8);
            const unsigned short* bu0 = (const unsigned short*)&b0;
            const unsigned short* bu1 = (const unsigned short*)&b1;
            half8 bf0, bf1;
#pragma unroll
            for (int j = 0; j < 8; ++j) {
                bf0[j] = (_Float16)(bf2f(bu0[j]) * vkf[j]);
                bf1[j] = (_Float16)(bf2f(bu1[j]) * vkf[j]);
            }
            oacc0 = __builtin_amdgcn_mfma_f32_16x16x32_f16(afr, bf0, oacc0, 0, 0, 0);
            oacc1 = __builtin_amdgcn_mfma_f32_16x16x32_f16(afr, bf1, oacc1, 0, 0, 0);
        }
        const int b = bh >> 3, h = bh & 7;
#pragma unroll
        for (int p = 0; p < 4; ++p) {
            const int lrow = m0 + rb * 16 + quad * 4 + p;
            const float uu = uls[rb * 16 + quad * 4 + p];
            const size_t base = ((size_t)((b << 10) + lrow)) * 512 + (h << 6);
            o_p[base + (jh * 2) * 16 + l16]     = f2bf(oacc0[p] * uu);
            o_p[base + (jh * 2 + 1) * 16 + l16] = f2bf(oacc1[p] * uu);
        }
    }
}

// ---------------- out = o_p(bf16 2048x512) @ Wo + bo : 64x64-tile MFMA ----------------
__global__ __launch_bounds__(256) void out64(
    const unsigned short* __restrict__ A, const unsigned short* __restrict__ BT,
    const float* __restrict__ bo, float* __restrict__ C)
{
    __shared__ __align__(16) unsigned short Als[64 * 72];
    __shared__ __align__(16) unsigned short Bls[64 * 72];
    const int t = threadIdx.x;
    const int m0 = blockIdx.y << 6, n0 = blockIdx.x << 6;
    const int w = t >> 6, lane = t & 63, quad = lane >> 4, l16 = lane & 15;
    const int lrow = t >> 2, lk = (t & 3) << 4;
    floatx4 acc[4] = {};
    for (int k0 = 0; k0 < 512; k0 += 64) {
        uint4 a0 = *(const uint4*)&A[(size_t)(m0 + lrow) * 512 + k0 + lk];
        uint4 a1 = *(const uint4*)&A[(size_t)(m0 + lrow) * 512 + k0 + lk + 8];
        uint4 b0 = *(const uint4*)&BT[(size_t)(n0 + lrow) * 512 + k0 + lk];
        uint4 b1 = *(const uint4*)&BT[(size_t)(n0 + lrow) * 512 + k0 + lk + 8];
        __syncthreads();
        *(uint4*)&Als[lrow * 72 + lk] = a0;
        *(uint4*)&Als[lrow * 72 + lk + 8] = a1;
        *(uint4*)&Bls[lrow * 72 + lk] = b0;
        *(uint4*)&Bls[lrow * 72 + lk + 8] = b1;
        __syncthreads();
        short8 af0 = *(const short8*)&Als[(w * 16 + l16) * 72 + quad * 8];
        short8 af1 = *(const short8*)&Als[(w * 16 + l16) * 72 + 32 + quad * 8];
#pragma unroll
        for (int nt = 0; nt < 4; ++nt) {
            short8 g0 = *(const short8*)&Bls[(nt * 16 + l16) * 72 + quad * 8];
            short8 g1 = *(const short8*)&Bls[(nt * 16 + l16) * 72 + 32 + quad * 8];
            acc[nt] = __builtin_amdgcn_mfma_f32_16x16x32_bf16(af0, g0, acc[nt], 0, 0, 0);
            acc[nt] = __builtin_amdgcn_mfma_f32_16x16x32_bf16(af1, g1, acc[nt], 0, 0, 0);
        }
    }
#pragma unroll
    for (int nt = 0; nt < 4; ++nt) {
        const int gn = n0 + nt * 16 + l16;
        const float bb = bo[gn];
#pragma unroll
        for (int p = 0; p < 4; ++p) {
            const int gm = m0 + w * 16 + quad * 4 + p;
            C[(size_t)gm * 1024 + gn] = acc[nt][p] + bb;
        }
    }
}

extern "C" void kernel_launch(void* const* d_in, const int* in_sizes, int n_in,
                              void* d_out, int out_size, void* d_ws, size_t ws_size,
                              hipStream_t stream)
{
    const float* x  = (const float*)d_in[0];
    const float* Wq = (const float*)d_in[1];
    const float* bq = (const float*)d_in[2];
    const float* Wk = (const float*)d_in[3];
    const float* bk = (const float*)d_in[4];
    const float* Wv = (const float*)d_in[5];
    const float* bv = (const float*)d_in[6];
    const float* Wo = (const float*)d_in[7];
    const float* bo = (const float*)d_in[8];
    float* out = (float*)d_out;

    char* W = (char*)d_ws;
    unsigned short* xb  = (unsigned short*)(W);                    // 4 MB
    unsigned short* wqT = (unsigned short*)(W + (4ll  << 20));     // 1 MB
    unsigned short* wkT = (unsigned short*)(W + (5ll  << 20));     // 1 MB
    unsigned short* wvT = (unsigned short*)(W + (6ll  << 20));     // 1 MB
    unsigned short* woT = (unsigned short*)(W + (7ll  << 20));     // 1 MB
    unsigned short* qb  = (unsigned short*)(W + (8ll  << 20));     // 2 MB
    unsigned short* kb  = (unsigned short*)(W + (10ll << 20));     // 2 MB
    unsigned short* vt  = (unsigned short*)(W + (12ll << 20));     // 2 MB
    unsigned short* o_p = (unsigned short*)(W + (14ll << 20));     // 2 MB
    float* part         = (float*)(W + (16ll << 20));              // 192 KB (3 bufs)
    unsigned int* ctr   = (unsigned int*)(W + (17ll << 20));       // 4 KB (padded)

    convert_x<<<512, 256, 0, stream>>>(x, xb);
    transpose_all<<<dim3(32, 32, 4), 256, 0, stream>>>(Wq, Wk, Wv, Wo, wqT, wkT, wvT, woT);
    zero_init<<<192, 256, 0, stream>>>(part, ctr);
    qkv64<<<dim3(8, 32, 3), 256, 0, stream>>>(xb, wqT, wkT, wvT, bq, bk, bv, qb, kb, vt);

    hipFuncSetAttribute((const void*)sinkhorn_persistent,
                        hipFuncAttributeMaxDynamicSharedMemorySize, SMEM_BYTES);
    void* kargs[] = { (void*)&qb, (void*)&kb, (void*)&vt, (void*)&o_p,
                      (void*)&part, (void*)&ctr };
    hipLaunchCooperativeKernel((const void*)sinkhorn_persistent, dim3(256), dim3(512),
                               kargs, SMEM_BYTES, stream);

    out64<<<dim3(16, 32), 256, 0, stream>>>(o_p, woT, bo, out);
}